// Round 4
// baseline (332.975 us; speedup 1.0000x reference)
//
#include <hip/hip_runtime.h>

typedef _Float16 f16;
typedef __attribute__((ext_vector_type(8))) _Float16 f16x8;
typedef __attribute__((ext_vector_type(4))) _Float16 f16x4;
typedef __attribute__((ext_vector_type(4))) float floatx4;

#define MFMA16(a, b, c) __builtin_amdgcn_mfma_f32_16x16x32_f16(a, b, c, 0, 0, 0)

#define BATCH 32
#define LQ 512
#define LK 512
#define DIM 1024

// raw barrier (no vmcnt drain) + counted vmem waits — T3/T4 pattern
#define BARRIER() __builtin_amdgcn_s_barrier()
#define CFENCE() asm volatile("" ::: "memory")
#define WAITVM(n) asm volatile("s_waitcnt vmcnt(" #n ")" ::: "memory")

// async global->LDS, 16B per lane. LDS dest must be base + lane*16 within wave.
__device__ __forceinline__ void glds16(const void* g, void* l) {
    __builtin_amdgcn_global_load_lds(
        (const __attribute__((address_space(1))) unsigned int*)g,
        (__attribute__((address_space(3))) unsigned int*)l, 16, 0, 0);
}

// LDS tile layout: [rows][32 f16] (64B rows). 16B-slot XOR swizzle with
// (row>>1)&3: 8 consecutive rows cover all eight 4-bank sets -> 2 lanes/set
// (free wave64 minimum). Staged by pre-swizzling the GLOBAL source slot
// (LDS dest stays linear for glds16), read with the same XOR.
// [(row&3) was wrong: rows r and r+4 collided -> residual 4-way.]
#define SWZ_F16(row, q) ((row) * 32 + (((q) ^ (((row) >> 1) & 3)) * 8))

// ---------------------------------------------------------------------------
// K0a stage 1: partial[ec][d] = sum_{e in 64-chunk ec} W[e][d]*bias[e]
// ---------------------------------------------------------------------------
__global__ __launch_bounds__(256) void k_cvec1(const float* __restrict__ W,
                                               const float* __restrict__ bias,
                                               float* __restrict__ partial) {
    __shared__ float red[256];
    int t = threadIdx.x;
    int dd = t & 63, eg = t >> 6;
    int d = blockIdx.x * 64 + dd;
    int e0 = blockIdx.y * 64 + eg * 16;
    float s = 0.f;
#pragma unroll
    for (int i = 0; i < 16; ++i)
        s += W[(size_t)(e0 + i) * DIM + d] * bias[e0 + i];
    red[t] = s;
    __syncthreads();
    if (eg == 0)
        partial[blockIdx.y * DIM + d] =
            red[dd] + red[64 + dd] + red[128 + dd] + red[192 + dd];
}

// K0a stage 2: c[d] = sum_ec partial[ec][d]
__global__ __launch_bounds__(256) void k_cvec2(const float* __restrict__ partial,
                                               float* __restrict__ c) {
    int d = blockIdx.x * 256 + threadIdx.x;
    float s = 0.f;
#pragma unroll
    for (int j = 0; j < 16; ++j) s += partial[j * DIM + d];
    c[d] = s;
}

// ---------------------------------------------------------------------------
// K0b: Y16 = fp16(Y) and z[row] = c . Y[row]   (grid 4096 x 256)
// ---------------------------------------------------------------------------
__global__ __launch_bounds__(256) void k_prep_y(const float* __restrict__ Y,
                                                const float* __restrict__ c,
                                                f16* __restrict__ Y16,
                                                float* __restrict__ z) {
    int wid = threadIdx.x >> 6, lane = threadIdx.x & 63;
    int row = blockIdx.x * 4 + wid;
    const float* yr = Y + (size_t)row * DIM;
    f16* orow = Y16 + (size_t)row * DIM;
    float s = 0.f;
#pragma unroll
    for (int k = 0; k < 4; ++k) {
        int d = k * 256 + lane * 4;
        floatx4 v = *(const floatx4*)(yr + d);
        floatx4 cv = *(const floatx4*)(c + d);
        s += v[0] * cv[0] + v[1] * cv[1] + v[2] * cv[2] + v[3] * cv[3];
        f16x4 o;
        o[0] = (f16)v[0]; o[1] = (f16)v[1]; o[2] = (f16)v[2]; o[3] = (f16)v[3];
        *(f16x4*)(orow + d) = o;
    }
#pragma unroll
    for (int off = 32; off; off >>= 1) s += __shfl_down(s, off, 64);
    if (lane == 0) z[row] = s;
}

// ---------------------------------------------------------------------------
// K0c: X16 = fp16(X)
// ---------------------------------------------------------------------------
__global__ __launch_bounds__(256) void k_xsplit(const float* __restrict__ X,
                                                f16* __restrict__ X16) {
    size_t i = ((size_t)blockIdx.x * 256 + threadIdx.x) * 8;
    floatx4 a = *(const floatx4*)(X + i);
    floatx4 b = *(const floatx4*)(X + i + 4);
    f16x8 o;
    o[0] = (f16)a[0]; o[1] = (f16)a[1]; o[2] = (f16)a[2]; o[3] = (f16)a[3];
    o[4] = (f16)b[0]; o[5] = (f16)b[1]; o[6] = (f16)b[2]; o[7] = (f16)b[3];
    *(f16x8*)(X16 + i) = o;
}

// ---------------------------------------------------------------------------
// K_wt16: WT[d][e] = fp16(W[e][d])  (fused transpose+convert, grid (16,16))
// ---------------------------------------------------------------------------
__global__ __launch_bounds__(256) void k_wt16(const float* __restrict__ W,
                                              f16* __restrict__ WT) {
    __shared__ __align__(16) f16 S[64][72];
    const int e0 = blockIdx.x * 64, d0 = blockIdx.y * 64;
    const int t = threadIdx.x;
    {
        int row = t >> 2, cg = (t & 3) * 16;
        const float* src = W + (size_t)(e0 + row) * DIM + d0 + cg;
#pragma unroll
        for (int h = 0; h < 4; ++h) {
            floatx4 v = *(const floatx4*)(src + h * 4);
            f16x4 o;
            o[0] = (f16)v[0]; o[1] = (f16)v[1]; o[2] = (f16)v[2]; o[3] = (f16)v[3];
            *(f16x4*)&S[row][cg + h * 4] = o;
        }
    }
    __syncthreads();
    int dd = t >> 2, ms = (t & 3) * 16;
    union { f16 h[16]; uint4 u[2]; } o;
#pragma unroll
    for (int j = 0; j < 16; ++j) o.h[j] = S[ms + j][dd];
    f16* dst = WT + (size_t)(d0 + dd) * DIM + e0 + ms;
    *(uint4*)dst = o.u[0];
    *(uint4*)(dst + 8) = o.u[1];
}

// ---------------------------------------------------------------------------
// K1: Gh = fp16(WT @ WT^T) = fp16(W^T W). 128x128 tile on fp16 WT, BK=32,
// glds staging + swizzle, counted-vmcnt pipeline. grid (8,8), 256 thr.
// ---------------------------------------------------------------------------
__global__ __launch_bounds__(256) void k_gram16(const f16* __restrict__ WT,
                                                f16* __restrict__ Gh) {
    __shared__ __align__(16) f16 sA[2][128 * 32];
    __shared__ __align__(16) f16 sB[2][128 * 32];
    const int t = threadIdx.x;
    const int lane = t & 63, wid = t >> 6;
    const int ln15 = lane & 15, q = lane >> 4;
    const int wr = (wid >> 1) * 64, wc = (wid & 1) * 64;
    const int i0 = blockIdx.x * 128, j0 = blockIdx.y * 128;
    floatx4 acc[4][4] = {};

    auto stage = [&](int buf, int e0) {  // 4 glds16 per thread per tile
#pragma unroll
        for (int is = 0; is < 2; ++is) {
            int p = is * 4096 + t * 16;
            int row = p >> 6;
            int c16 = ((p & 63) >> 4) ^ ((row >> 1) & 3);
            glds16(WT + (size_t)(i0 + row) * DIM + e0 + c16 * 8,
                   (char*)&sA[buf][0] + p);
            glds16(WT + (size_t)(j0 + row) * DIM + e0 + c16 * 8,
                   (char*)&sB[buf][0] + p);
        }
    };
    auto compute = [&](int buf) {
        f16x8 a[4];
#pragma unroll
        for (int mi = 0; mi < 4; ++mi)
            a[mi] = *(const f16x8*)&sA[buf][SWZ_F16(wr + mi * 16 + ln15, q)];
#pragma unroll
        for (int ni = 0; ni < 4; ++ni) {
            f16x8 bv = *(const f16x8*)&sB[buf][SWZ_F16(wc + ni * 16 + ln15, q)];
#pragma unroll
            for (int mi = 0; mi < 4; ++mi)
                acc[mi][ni] = MFMA16(a[mi], bv, acc[mi][ni]);
        }
    };

    stage(0, 0);
    stage(1, 32);
    for (int tt = 0; tt < 32; ++tt) {
        if (tt < 31) { WAITVM(4); } else { WAITVM(0); }
        BARRIER();
        CFENCE();
        __builtin_amdgcn_s_setprio(1);
        compute(tt & 1);
        __builtin_amdgcn_s_setprio(0);
        CFENCE();
        BARRIER();
        if (tt < 30) stage(tt & 1, (tt + 2) * 32);
    }

#pragma unroll
    for (int mi = 0; mi < 4; ++mi)
#pragma unroll
        for (int ni = 0; ni < 4; ++ni)
#pragma unroll
            for (int r = 0; r < 4; ++r)
                Gh[(size_t)(i0 + wr + mi * 16 + q * 4 + r) * DIM +
                   j0 + wc + ni * 16 + ln15] = (f16)acc[mi][ni][r];
}

// ---------------------------------------------------------------------------
// K2: Th = fp16(X16 @ Gh). 128x128 tile, 256 thr, BK=32, glds staging +
// swizzle, counted-vmcnt. grid (128,8) = 4 blocks/CU (cross-block overlap
// is the latency hiding -- 256^2/1-block-CU regressed, reverted).
// ---------------------------------------------------------------------------
__global__ __launch_bounds__(256) void k_tgemm(const f16* __restrict__ X16,
                                               const f16* __restrict__ Gh,
                                               f16* __restrict__ Th) {
    __shared__ __align__(16) f16 sA[2][128 * 32];
    __shared__ __align__(16) f16 sB[2][128 * 32];
    const int t = threadIdx.x;
    const int lane = t & 63, wid = t >> 6;
    const int ln15 = lane & 15, q = lane >> 4;
    const int wr = (wid >> 1) * 64, wc = (wid & 1) * 64;
    const int m0 = blockIdx.x * 128, n0 = blockIdx.y * 128;
    floatx4 acc[4][4] = {};

    auto stage = [&](int buf, int e0) {  // 4 glds16 per thread per tile
#pragma unroll
        for (int is = 0; is < 2; ++is) {
            int p = is * 4096 + t * 16;
            int row = p >> 6;
            int c16 = ((p & 63) >> 4) ^ ((row >> 1) & 3);
            glds16(X16 + (size_t)(m0 + row) * DIM + e0 + c16 * 8,
                   (char*)&sA[buf][0] + p);
            glds16(Gh + (size_t)(n0 + row) * DIM + e0 + c16 * 8,
                   (char*)&sB[buf][0] + p);
        }
    };
    auto compute = [&](int buf) {
        f16x8 a[4];
#pragma unroll
        for (int mi = 0; mi < 4; ++mi)
            a[mi] = *(const f16x8*)&sA[buf][SWZ_F16(wr + mi * 16 + ln15, q)];
#pragma unroll
        for (int ni = 0; ni < 4; ++ni) {
            f16x8 bv = *(const f16x8*)&sB[buf][SWZ_F16(wc + ni * 16 + ln15, q)];
#pragma unroll
            for (int mi = 0; mi < 4; ++mi)
                acc[mi][ni] = MFMA16(a[mi], bv, acc[mi][ni]);
        }
    };

    stage(0, 0);
    stage(1, 32);
    for (int tt = 0; tt < 32; ++tt) {
        if (tt < 31) { WAITVM(4); } else { WAITVM(0); }
        BARRIER();
        CFENCE();
        __builtin_amdgcn_s_setprio(1);
        compute(tt & 1);
        __builtin_amdgcn_s_setprio(0);
        CFENCE();
        BARRIER();
        if (tt < 30) stage(tt & 1, (tt + 2) * 32);
    }

#pragma unroll
    for (int mi = 0; mi < 4; ++mi)
#pragma unroll
        for (int ni = 0; ni < 4; ++ni)
#pragma unroll
            for (int r = 0; r < 4; ++r)
                Th[(size_t)(m0 + wr + mi * 16 + q * 4 + r) * DIM +
                   n0 + wc + ni * 16 + ln15] = (f16)acc[mi][ni][r];
}

// ---------------------------------------------------------------------------
// K_yT: YT16[b][d][m] = Y16[b][m][d]   (grid (32,8,16), 64x64 tiles)
// ---------------------------------------------------------------------------
__global__ __launch_bounds__(256) void k_ytrans(const f16* __restrict__ Y16,
                                                f16* __restrict__ YT) {
    __shared__ __align__(16) f16 S[64][72];
    const int b = blockIdx.x, m0 = blockIdx.y * 64, d0 = blockIdx.z * 64;
    const int t = threadIdx.x;
    {
        int row = t >> 2, cg = (t & 3) * 16;
        const f16* src = Y16 + (size_t)(b * LK + m0 + row) * DIM + d0 + cg;
        *(uint4*)&S[row][cg] = *(const uint4*)src;
        *(uint4*)&S[row][cg + 8] = *(const uint4*)(src + 8);
    }
    __syncthreads();
    int dd = t >> 2, ms = (t & 3) * 16;
    union { f16 h[16]; uint4 u[2]; } o;
#pragma unroll
    for (int j = 0; j < 16; ++j) o.h[j] = S[ms + j][dd];
    f16* dst = YT + (size_t)(b * DIM + d0 + dd) * LK + m0 + ms;
    *(uint4*)dst = o.u[0];
    *(uint4*)(dst + 8) = o.u[1];
}

// ---------------------------------------------------------------------------
// K3: per (b, 64 q-rows): s = Th . Y16^T + z, softmax over 512 keys,
// write unnormalized P fp16 + row sums. 512 thr (8 waves), grid 256 (1D).
// XCD swizzle: linear_id%8 == b%8 -> all 8 q-tiles of a batch land on one
// XCD, making the 8x re-read of that batch's 1MB Y16 L2-local instead of
// 8 L3 streams. 3-deep counted-vmcnt pipeline (2 steps of slack vs L2/L3
// latency; LDS 3x36KB, still 1 block/CU). LDS swizzled ((row>>1)&3).
// ---------------------------------------------------------------------------
__global__ __launch_bounds__(512) void k_attn(const f16* __restrict__ Th,
                                              const f16* __restrict__ Y16,
                                              const float* __restrict__ Z,
                                              f16* __restrict__ P,
                                              float* __restrict__ Lsum) {
    __shared__ __align__(16) f16 sS[3][18432];  // 3 x 36864 B
    __shared__ float redmax[64][8];
    __shared__ float redsum[64][8];
    const int g = blockIdx.x;
    const int b = (g & 7) + 8 * (g >> 6);        // XCD-affine batch decode
    const int l0 = ((g >> 3) & 7) * 64;
    const int t = threadIdx.x;
    const int lane = t & 63, w = t >> 6;
    const int ln15 = lane & 15, q = lane >> 4;
    const bool heavy = (t < 256);  // waves 0-3 issue 5 glds/tile
    floatx4 acc[4][4] = {};

    auto stage = [&](int buf, int e0) {
#pragma unroll
        for (int is = 0; is < 4; ++is) {
            int ff = is * 8192 + t * 16;
            const f16* g2;
            if (ff < 4096) {  // wave-uniform (boundary at t=256)
                int row = ff >> 6;
                int c16 = ((ff & 63) >> 4) ^ ((row >> 1) & 3);
                g2 = Th + (size_t)(b * LQ + l0 + row) * DIM + e0 + c16 * 8;
            } else {
                int f2 = ff - 4096;
                int row = f2 >> 6;
                int c16 = ((f2 & 63) >> 4) ^ ((row >> 1) & 3);
                g2 = Y16 + (size_t)(b * LK + row) * DIM + e0 + c16 * 8;
            }
            glds16(g2, (char*)&sS[buf][0] + ff);
        }
        if (heavy) {  // last 4KB chunk
            int ff = 32768 + t * 16;
            int f2 = ff - 4096;
            int row = f2 >> 6;
            int c16 = ((f2 & 63) >> 4) ^ ((row >> 1) & 3);
            const f16* g2 = Y16 + (size_t)(b * LK + row) * DIM + e0 + c16 * 8;
            glds16(g2, (char*)&sS[buf][0] + ff);
        }
    };
    auto compute = [&](int buf) {
        f16x8 th[4];
#pragma unroll
        for (int mi = 0; mi < 4; ++mi)
            th[mi] = *(const f16x8*)&sS[buf][SWZ_F16(mi * 16 + ln15, q)];
#pragma unroll
        for (int ni = 0; ni < 4; ++ni) {
            f16x8 y = *(const f16x8*)&sS[buf][2048 + SWZ_F16(w * 64 + ni * 16 + ln15, q)];
#pragma unroll
            for (int mi = 0; mi < 4; ++mi)
                acc[mi][ni] = MFMA16(th[mi], y, acc[mi][ni]);
        }
    };

    stage(0, 0);
    stage(1, 32);
    stage(2, 64);
    int cur = 0;
    for (int tt = 0; tt < 32; ++tt) {
        // wait until tile tt's loads landed (2 future tiles may stay in flight)
        if (tt < 30) {
            if (heavy) { WAITVM(10); } else { WAITVM(8); }
        } else if (tt == 30) {
            if (heavy) { WAITVM(5); } else { WAITVM(4); }
        } else {
            WAITVM(0);
        }
        BARRIER();
        CFENCE();
        __builtin_amdgcn_s_setprio(1);
        compute(cur);
        __builtin_amdgcn_s_setprio(0);
        CFENCE();
        BARRIER();
        if (tt < 29) stage(cur, (tt + 3) * 32);
        cur = (cur == 2) ? 0 : cur + 1;
    }

    // ---- softmax over 512 cols (8 waves x 64 cols) ----
    float zv[4];
#pragma unroll
    for (int ni = 0; ni < 4; ++ni) zv[ni] = Z[b * LK + w * 64 + ni * 16 + ln15];

    float rmx[4][4];
#pragma unroll
    for (int mi = 0; mi < 4; ++mi)
#pragma unroll
        for (int r = 0; r < 4; ++r) {
            float m = -3.0e38f;
#pragma unroll
            for (int ni = 0; ni < 4; ++ni) m = fmaxf(m, acc[mi][ni][r] + zv[ni]);
#pragma unroll
            for (int off = 1; off < 16; off <<= 1) m = fmaxf(m, __shfl_xor(m, off, 64));
            rmx[mi][r] = m;
        }
    if (ln15 == 0) {
#pragma unroll
        for (int mi = 0; mi < 4; ++mi)
#pragma unroll
            for (int r = 0; r < 4; ++r) redmax[mi * 16 + q * 4 + r][w] = rmx[mi][r];
    }
    __syncthreads();
#pragma unroll
    for (int mi = 0; mi < 4; ++mi)
#pragma unroll
        for (int r = 0; r < 4; ++r) {
            int row = mi * 16 + q * 4 + r;
            float m = redmax[row][0];
#pragma unroll
            for (int j = 1; j < 8; ++j) m = fmaxf(m, redmax[row][j]);
            rmx[mi][r] = m;
        }
    float rsm[4][4] = {};
#pragma unroll
    for (int mi = 0; mi < 4; ++mi)
#pragma unroll
        for (int ni = 0; ni < 4; ++ni)
#pragma unroll
            for (int r = 0; r < 4; ++r) {
                float e = __expf(acc[mi][ni][r] + zv[ni] - rmx[mi][r]);
                acc[mi][ni][r] = e;
                rsm[mi][r] += e;
            }
#pragma unroll
    for (int mi = 0; mi < 4; ++mi)
#pragma unroll
        for (int r = 0; r < 4; ++r) {
            float s = rsm[mi][r];
#pragma unroll
            for (int off = 1; off < 16; off <<= 1) s += __shfl_xor(s, off, 64);
            rsm[mi][r] = s;
        }
    if (ln15 == 0) {
#pragma unroll
        for (int mi = 0; mi < 4; ++mi)
#pragma unroll
            for (int r = 0; r < 4; ++r) redsum[mi * 16 + q * 4 + r][w] = rsm[mi][r];
    }
    __syncthreads();
    if (w == 0 && ln15 == 0) {
#pragma unroll
        for (int mi = 0; mi < 4; ++mi)
#pragma unroll
            for (int r = 0; r < 4; ++r) {
                int row = mi * 16 + q * 4 + r;
                float s = 0.f;
#pragma unroll
                for (int j = 0; j < 8; ++j) s += redsum[row][j];
                Lsum[b * LQ + l0 + row] = s;
            }
    }
#pragma unroll
    for (int mi = 0; mi < 4; ++mi)
#pragma unroll
        for (int ni = 0; ni < 4; ++ni)
#pragma unroll
            for (int r = 0; r < 4; ++r) {
                int row = l0 + mi * 16 + q * 4 + r;
                int col = w * 64 + ni * 16 + ln15;
                P[(size_t)(b * LQ + row) * LK + col] = (f16)acc[mi][ni][r];
            }
}

// ---------------------------------------------------------------------------
// K4: O = (P @ y) / Lsum via YT16. 128x128 tile, 256 thr, BK=32, glds +
// swizzle, counted-vmcnt, grid 1024 (1D) with XCD batch-affinity
// (linear_id%8 == b%8: the 32 blocks sharing a batch's P+YT go to one XCD).
// ---------------------------------------------------------------------------
__global__ __launch_bounds__(256) void k_pv(const f16* __restrict__ P,
                                            const f16* __restrict__ YT,
                                            const float* __restrict__ Lsum,
                                            float* __restrict__ O) {
    __shared__ __align__(16) f16 sA[2][128 * 32];
    __shared__ __align__(16) f16 sB[2][128 * 32];
    const int t = threadIdx.x;
    const int lane = t & 63, wid = t >> 6;
    const int ln15 = lane & 15, q = lane >> 4;
    const int wr = (wid >> 1) * 64, wc = (wid & 1) * 64;
    const int g = blockIdx.x;
    const int b = (g & 7) + 8 * (g >> 8);        // XCD-affine batch decode
    const int inner = (g >> 3) & 31;
    const int m0 = (inner >> 3) * 128, n0 = (inner & 7) * 128;
    floatx4 acc[4][4] = {};

    auto stage = [&](int buf, int k0) {  // 4 glds16 per thread per tile
#pragma unroll
        for (int is = 0; is < 2; ++is) {
            int p = is * 4096 + t * 16;
            int row = p >> 6;
            int c16 = ((p & 63) >> 4) ^ ((row >> 1) & 3);
            glds16(P + (size_t)(b * LQ + m0 + row) * LK + k0 + c16 * 8,
                   (char*)&sA[buf][0] + p);
            glds16(YT + (size_t)(b * DIM + n0 + row) * LK + k0 + c16 * 8,
                   (char*)&sB[buf][0] + p);
        }
    };
    auto compute = [&](int buf) {
        f16x8 a[4];
#pragma unroll
        for (int mi = 0; mi < 4; ++mi)
            a[mi] = *(const f16x8*)&sA[buf][SWZ_F16(wr + mi * 16 + ln15, q)];
#pragma unroll
        for (int ni = 0; ni < 4; ++ni) {
            f16x8 bv = *(const f16x8*)&sB[buf][SWZ_F16(wc + ni * 16 + ln15, q)];
#pragma unroll
            for (int mi = 0; mi < 4; ++mi) acc[mi][ni] = MFMA16(a[mi], bv, acc[mi][ni]);
        }
    };

    stage(0, 0);
    stage(1, 32);
    for (int tt = 0; tt < 16; ++tt) {
        if (tt < 15) { WAITVM(4); } else { WAITVM(0); }
        BARRIER();
        CFENCE();
        __builtin_amdgcn_s_setprio(1);
        compute(tt & 1);
        __builtin_amdgcn_s_setprio(0);
        CFENCE();
        BARRIER();
        if (tt < 14) stage(tt & 1, (tt + 2) * 32);
    }

    float invl[4][4];
#pragma unroll
    for (int mi = 0; mi < 4; ++mi)
#pragma unroll
        for (int r = 0; r < 4; ++r)
            invl[mi][r] = 1.0f / Lsum[b * LQ + m0 + wr + mi * 16 + q * 4 + r];
#pragma unroll
    for (int mi = 0; mi < 4; ++mi)
#pragma unroll
        for (int ni = 0; ni < 4; ++ni)
#pragma unroll
            for (int r = 0; r < 4; ++r)
                O[(size_t)(b * LQ + m0 + wr + mi * 16 + q * 4 + r) * DIM +
                  n0 + wc + ni * 16 + ln15] = acc[mi][ni][r] * invl[mi][r];
}

// ---------------------------------------------------------------------------
// Workspace layout (bytes), total ~86 MiB:
//   A:  0         X16 fp16 [16384][1024] (33,554,432); reused as YT16 after tgemm
//   B:  33554432  Y16 fp16 [32][512][1024] (33,554,432)
//   P:  67108864  P fp16 [32][512][512]    (16,777,216)
//       (head of P region doubles as WT16 fp16 [1024][1024] (2MB) before k_attn)
//   Gh: 83886080  (2,097,152)
//   c:  85983232 (4096)  z: 85987328 (65536)  L: 86052864 (65536)
//   partial: 86118400 (65536)
// d_out doubles as Th fp16 scratch (32 MB) between k_tgemm and k_attn;
// k_pv overwrites it with the final fp32 result.
// ---------------------------------------------------------------------------
extern "C" void kernel_launch(void* const* d_in, const int* in_sizes, int n_in,
                              void* d_out, int out_size, void* d_ws, size_t ws_size,
                              hipStream_t stream) {
    const float* ix = (const float*)d_in[0];
    const float* io = (const float*)d_in[1];
    const float* W = (const float*)d_in[2];
    const float* bb = (const float*)d_in[3];
    float* out = (float*)d_out;
    char* ws = (char*)d_ws;

    f16* X16 = (f16*)(ws);
    f16* YT16 = (f16*)(ws);  // same region, used after k_tgemm
    f16* Y16 = (f16*)(ws + 33554432);
    f16* P = (f16*)(ws + 67108864);
    f16* WT = (f16*)(ws + 67108864);  // overlays P region; dead before k_attn
    f16* Gh = (f16*)(ws + 83886080);
    float* c = (float*)(ws + 85983232);
    float* z = (float*)(ws + 85987328);
    float* L = (float*)(ws + 86052864);
    float* partial = (float*)(ws + 86118400);

    f16* Th = (f16*)d_out;

    k_cvec1<<<dim3(16, 16), dim3(256), 0, stream>>>(W, bb, partial);
    k_cvec2<<<dim3(4), dim3(256), 0, stream>>>(partial, c);
    k_wt16<<<dim3(16, 16), dim3(256), 0, stream>>>(W, WT);
    k_gram16<<<dim3(8, 8), dim3(256), 0, stream>>>(WT, Gh);
    k_prep_y<<<dim3(4096), dim3(256), 0, stream>>>(io, c, Y16, z);
    k_xsplit<<<dim3(8192), dim3(256), 0, stream>>>(ix, X16);
    k_tgemm<<<dim3(128, 8), dim3(256), 0, stream>>>(X16, Gh, Th);
    k_ytrans<<<dim3(32, 8, 16), dim3(256), 0, stream>>>(Y16, YT16);
    k_attn<<<dim3(256), dim3(512), 0, stream>>>(Th, Y16, z, P, L);
    k_pv<<<dim3(1024), dim3(256), 0, stream>>>(P, YT16, L, out);
}

// Round 5
// 329.912 us; speedup vs baseline: 1.0093x; 1.0093x over previous
//
#include <hip/hip_runtime.h>

typedef _Float16 f16;
typedef __attribute__((ext_vector_type(8))) _Float16 f16x8;
typedef __attribute__((ext_vector_type(4))) _Float16 f16x4;
typedef __attribute__((ext_vector_type(4))) float floatx4;

#define MFMA16(a, b, c) __builtin_amdgcn_mfma_f32_16x16x32_f16(a, b, c, 0, 0, 0)

#define BATCH 32
#define LQ 512
#define LK 512
#define DIM 1024

// raw barrier (no vmcnt drain) + counted vmem waits — T3/T4 pattern
#define BARRIER() __builtin_amdgcn_s_barrier()
#define CFENCE() asm volatile("" ::: "memory")
#define WAITVM(n) asm volatile("s_waitcnt vmcnt(" #n ")" ::: "memory")

// async global->LDS, 16B per lane. LDS dest must be base + lane*16 within wave.
// NOTE (round-4 lesson): do NOT pre-swizzle the global source address — the
// permuted 16B chunks break intra-wave request coalescing (FETCH +66%,
// VALU +16pts, net −22% on tgemm). The LDS bank conflicts the swizzle would
// fix are off the critical path in this 2-barrier counted-vmcnt schedule.
__device__ __forceinline__ void glds16(const void* g, void* l) {
    __builtin_amdgcn_global_load_lds(
        (const __attribute__((address_space(1))) unsigned int*)g,
        (__attribute__((address_space(3))) unsigned int*)l, 16, 0, 0);
}

// ---------------------------------------------------------------------------
// K0a stage 1: partial[ec][d] = sum_{e in 64-chunk ec} W[e][d]*bias[e]
// ---------------------------------------------------------------------------
__global__ __launch_bounds__(256) void k_cvec1(const float* __restrict__ W,
                                               const float* __restrict__ bias,
                                               float* __restrict__ partial) {
    __shared__ float red[256];
    int t = threadIdx.x;
    int dd = t & 63, eg = t >> 6;
    int d = blockIdx.x * 64 + dd;
    int e0 = blockIdx.y * 64 + eg * 16;
    float s = 0.f;
#pragma unroll
    for (int i = 0; i < 16; ++i)
        s += W[(size_t)(e0 + i) * DIM + d] * bias[e0 + i];
    red[t] = s;
    __syncthreads();
    if (eg == 0)
        partial[blockIdx.y * DIM + d] =
            red[dd] + red[64 + dd] + red[128 + dd] + red[192 + dd];
}

// K0a stage 2: c[d] = sum_ec partial[ec][d]
__global__ __launch_bounds__(256) void k_cvec2(const float* __restrict__ partial,
                                               float* __restrict__ c) {
    int d = blockIdx.x * 256 + threadIdx.x;
    float s = 0.f;
#pragma unroll
    for (int j = 0; j < 16; ++j) s += partial[j * DIM + d];
    c[d] = s;
}

// ---------------------------------------------------------------------------
// K0b: Y16 = fp16(Y) and z[row] = c . Y[row]   (grid 4096 x 256)
// ---------------------------------------------------------------------------
__global__ __launch_bounds__(256) void k_prep_y(const float* __restrict__ Y,
                                                const float* __restrict__ c,
                                                f16* __restrict__ Y16,
                                                float* __restrict__ z) {
    int wid = threadIdx.x >> 6, lane = threadIdx.x & 63;
    int row = blockIdx.x * 4 + wid;
    const float* yr = Y + (size_t)row * DIM;
    f16* orow = Y16 + (size_t)row * DIM;
    float s = 0.f;
#pragma unroll
    for (int k = 0; k < 4; ++k) {
        int d = k * 256 + lane * 4;
        floatx4 v = *(const floatx4*)(yr + d);
        floatx4 cv = *(const floatx4*)(c + d);
        s += v[0] * cv[0] + v[1] * cv[1] + v[2] * cv[2] + v[3] * cv[3];
        f16x4 o;
        o[0] = (f16)v[0]; o[1] = (f16)v[1]; o[2] = (f16)v[2]; o[3] = (f16)v[3];
        *(f16x4*)(orow + d) = o;
    }
#pragma unroll
    for (int off = 32; off; off >>= 1) s += __shfl_down(s, off, 64);
    if (lane == 0) z[row] = s;
}

// ---------------------------------------------------------------------------
// K0c: X16 = fp16(X)
// ---------------------------------------------------------------------------
__global__ __launch_bounds__(256) void k_xsplit(const float* __restrict__ X,
                                                f16* __restrict__ X16) {
    size_t i = ((size_t)blockIdx.x * 256 + threadIdx.x) * 8;
    floatx4 a = *(const floatx4*)(X + i);
    floatx4 b = *(const floatx4*)(X + i + 4);
    f16x8 o;
    o[0] = (f16)a[0]; o[1] = (f16)a[1]; o[2] = (f16)a[2]; o[3] = (f16)a[3];
    o[4] = (f16)b[0]; o[5] = (f16)b[1]; o[6] = (f16)b[2]; o[7] = (f16)b[3];
    *(f16x8*)(X16 + i) = o;
}

// ---------------------------------------------------------------------------
// K_wt16: WT[d][e] = fp16(W[e][d])  (fused transpose+convert, grid (16,16))
// ---------------------------------------------------------------------------
__global__ __launch_bounds__(256) void k_wt16(const float* __restrict__ W,
                                              f16* __restrict__ WT) {
    __shared__ __align__(16) f16 S[64][72];
    const int e0 = blockIdx.x * 64, d0 = blockIdx.y * 64;
    const int t = threadIdx.x;
    {
        int row = t >> 2, cg = (t & 3) * 16;
        const float* src = W + (size_t)(e0 + row) * DIM + d0 + cg;
#pragma unroll
        for (int h = 0; h < 4; ++h) {
            floatx4 v = *(const floatx4*)(src + h * 4);
            f16x4 o;
            o[0] = (f16)v[0]; o[1] = (f16)v[1]; o[2] = (f16)v[2]; o[3] = (f16)v[3];
            *(f16x4*)&S[row][cg + h * 4] = o;
        }
    }
    __syncthreads();
    int dd = t >> 2, ms = (t & 3) * 16;
    union { f16 h[16]; uint4 u[2]; } o;
#pragma unroll
    for (int j = 0; j < 16; ++j) o.h[j] = S[ms + j][dd];
    f16* dst = WT + (size_t)(d0 + dd) * DIM + e0 + ms;
    *(uint4*)dst = o.u[0];
    *(uint4*)(dst + 8) = o.u[1];
}

// ---------------------------------------------------------------------------
// K1: Gh = fp16(WT @ WT^T) = fp16(W^T W). 128x128 tile on fp16 WT, BK=32,
// linear glds staging, counted-vmcnt pipeline. grid (8,8), 256 thr.
// ---------------------------------------------------------------------------
__global__ __launch_bounds__(256) void k_gram16(const f16* __restrict__ WT,
                                                f16* __restrict__ Gh) {
    __shared__ __align__(16) f16 sA[2][128 * 32];
    __shared__ __align__(16) f16 sB[2][128 * 32];
    const int t = threadIdx.x;
    const int lane = t & 63, wid = t >> 6;
    const int ln15 = lane & 15, q = lane >> 4;
    const int wr = (wid >> 1) * 64, wc = (wid & 1) * 64;
    const int i0 = blockIdx.x * 128, j0 = blockIdx.y * 128;
    floatx4 acc[4][4] = {};

    const int srow = t >> 2, scol = (t & 3) * 8;
    const f16* gA = WT + (size_t)(i0 + srow) * DIM + scol;
    const f16* gB = WT + (size_t)(j0 + srow) * DIM + scol;

    auto stage = [&](int buf, int e0) {  // 4 glds16 per thread per tile
#pragma unroll
        for (int is = 0; is < 2; ++is) {
            glds16(gA + (size_t)(is * 64) * DIM + e0,
                   (char*)&sA[buf][0] + is * 4096 + t * 16);
            glds16(gB + (size_t)(is * 64) * DIM + e0,
                   (char*)&sB[buf][0] + is * 4096 + t * 16);
        }
    };
    auto compute = [&](int buf) {
        f16x8 a[4];
#pragma unroll
        for (int mi = 0; mi < 4; ++mi)
            a[mi] = *(const f16x8*)&sA[buf][(wr + mi * 16 + ln15) * 32 + q * 8];
#pragma unroll
        for (int ni = 0; ni < 4; ++ni) {
            f16x8 bv = *(const f16x8*)&sB[buf][(wc + ni * 16 + ln15) * 32 + q * 8];
#pragma unroll
            for (int mi = 0; mi < 4; ++mi)
                acc[mi][ni] = MFMA16(a[mi], bv, acc[mi][ni]);
        }
    };

    stage(0, 0);
    stage(1, 32);
    for (int tt = 0; tt < 32; ++tt) {
        if (tt < 31) { WAITVM(4); } else { WAITVM(0); }
        BARRIER();
        CFENCE();
        __builtin_amdgcn_s_setprio(1);
        compute(tt & 1);
        __builtin_amdgcn_s_setprio(0);
        CFENCE();
        BARRIER();
        if (tt < 30) stage(tt & 1, (tt + 2) * 32);
    }

#pragma unroll
    for (int mi = 0; mi < 4; ++mi)
#pragma unroll
        for (int ni = 0; ni < 4; ++ni)
#pragma unroll
            for (int r = 0; r < 4; ++r)
                Gh[(size_t)(i0 + wr + mi * 16 + q * 4 + r) * DIM +
                   j0 + wc + ni * 16 + ln15] = (f16)acc[mi][ni][r];
}

// ---------------------------------------------------------------------------
// K2: Th = fp16(X16 @ Gh). 128x128 tile, 256 thr, BK=32, linear glds
// staging, counted-vmcnt. grid (128,8) = 4 blocks/CU (cross-block overlap
// does the latency hiding; proven 48.6 us in round 2 — restored verbatim).
// ---------------------------------------------------------------------------
__global__ __launch_bounds__(256) void k_tgemm(const f16* __restrict__ X16,
                                               const f16* __restrict__ Gh,
                                               f16* __restrict__ Th) {
    __shared__ __align__(16) f16 sA[2][128 * 32];
    __shared__ __align__(16) f16 sB[2][128 * 32];
    const int t = threadIdx.x;
    const int lane = t & 63, wid = t >> 6;
    const int ln15 = lane & 15, q = lane >> 4;
    const int wr = (wid >> 1) * 64, wc = (wid & 1) * 64;
    const int m0 = blockIdx.x * 128, n0 = blockIdx.y * 128;
    floatx4 acc[4][4] = {};

    const int srow = t >> 2, scol = (t & 3) * 8;
    const f16* gA = X16 + (size_t)(m0 + srow) * DIM + scol;
    const f16* gB = Gh + (size_t)(n0 + srow) * DIM + scol;

    auto stage = [&](int buf, int e0) {  // 4 glds16 per thread per tile
#pragma unroll
        for (int is = 0; is < 2; ++is) {
            glds16(gA + (size_t)(is * 64) * DIM + e0,
                   (char*)&sA[buf][0] + is * 4096 + t * 16);
            glds16(gB + (size_t)(is * 64) * DIM + e0,
                   (char*)&sB[buf][0] + is * 4096 + t * 16);
        }
    };
    auto compute = [&](int buf) {
        f16x8 a[4];
#pragma unroll
        for (int mi = 0; mi < 4; ++mi)
            a[mi] = *(const f16x8*)&sA[buf][(wr + mi * 16 + ln15) * 32 + q * 8];
#pragma unroll
        for (int ni = 0; ni < 4; ++ni) {
            f16x8 bv = *(const f16x8*)&sB[buf][(wc + ni * 16 + ln15) * 32 + q * 8];
#pragma unroll
            for (int mi = 0; mi < 4; ++mi)
                acc[mi][ni] = MFMA16(a[mi], bv, acc[mi][ni]);
        }
    };

    stage(0, 0);
    stage(1, 32);
    for (int tt = 0; tt < 32; ++tt) {
        if (tt < 31) { WAITVM(4); } else { WAITVM(0); }
        BARRIER();
        CFENCE();
        __builtin_amdgcn_s_setprio(1);
        compute(tt & 1);
        __builtin_amdgcn_s_setprio(0);
        CFENCE();
        BARRIER();
        if (tt < 30) stage(tt & 1, (tt + 2) * 32);
    }

#pragma unroll
    for (int mi = 0; mi < 4; ++mi)
#pragma unroll
        for (int ni = 0; ni < 4; ++ni)
#pragma unroll
            for (int r = 0; r < 4; ++r)
                Th[(size_t)(m0 + wr + mi * 16 + q * 4 + r) * DIM +
                   n0 + wc + ni * 16 + ln15] = (f16)acc[mi][ni][r];
}

// ---------------------------------------------------------------------------
// K_yT: YT16[b][d][m] = Y16[b][m][d]   (grid (32,8,16), 64x64 tiles)
// ---------------------------------------------------------------------------
__global__ __launch_bounds__(256) void k_ytrans(const f16* __restrict__ Y16,
                                                f16* __restrict__ YT) {
    __shared__ __align__(16) f16 S[64][72];
    const int b = blockIdx.x, m0 = blockIdx.y * 64, d0 = blockIdx.z * 64;
    const int t = threadIdx.x;
    {
        int row = t >> 2, cg = (t & 3) * 16;
        const f16* src = Y16 + (size_t)(b * LK + m0 + row) * DIM + d0 + cg;
        *(uint4*)&S[row][cg] = *(const uint4*)src;
        *(uint4*)&S[row][cg + 8] = *(const uint4*)(src + 8);
    }
    __syncthreads();
    int dd = t >> 2, ms = (t & 3) * 16;
    union { f16 h[16]; uint4 u[2]; } o;
#pragma unroll
    for (int j = 0; j < 16; ++j) o.h[j] = S[ms + j][dd];
    f16* dst = YT + (size_t)(b * DIM + d0 + dd) * LK + m0 + ms;
    *(uint4*)dst = o.u[0];
    *(uint4*)(dst + 8) = o.u[1];
}

// ---------------------------------------------------------------------------
// K3: per (b, 64 q-rows): s = Th . Y16^T + z, softmax over 512 keys,
// write unnormalized P fp16 + row sums. 512 thr (8 waves), grid 256 (1D).
// XCD batch-affinity: linear_id%8 == b%8 -> all 8 q-tiles of a batch land
// on one XCD (its 1MB Y16 becomes L2-local across the 8x re-read).
// 3-deep counted-vmcnt pipeline (2 steps of slack vs L2/L3 latency;
// LDS 3x36KB, 1 block/CU). Linear staging (no source swizzle).
// ---------------------------------------------------------------------------
__global__ __launch_bounds__(512) void k_attn(const f16* __restrict__ Th,
                                              const f16* __restrict__ Y16,
                                              const float* __restrict__ Z,
                                              f16* __restrict__ P,
                                              float* __restrict__ Lsum) {
    __shared__ __align__(16) f16 sS[3][18432];  // 3 x 36864 B
    __shared__ float redmax[64][8];
    __shared__ float redsum[64][8];
    const int g = blockIdx.x;
    const int b = (g & 7) + 8 * (g >> 6);        // XCD-affine batch decode
    const int l0 = ((g >> 3) & 7) * 64;
    const int t = threadIdx.x;
    const int lane = t & 63, w = t >> 6;
    const int ln15 = lane & 15, q = lane >> 4;
    const bool heavy = (t < 256);  // waves 0-3 issue 5 glds/tile
    floatx4 acc[4][4] = {};

    auto stage = [&](int buf, int e0) {
#pragma unroll
        for (int is = 0; is < 4; ++is) {
            int ff = is * 8192 + t * 16;
            const f16* g2;
            if (ff < 4096) {  // wave-uniform (boundary at t=256)
                g2 = Th + (size_t)(b * LQ + l0 + (ff >> 6)) * DIM + e0 + ((ff & 63) >> 1);
            } else {
                int f2 = ff - 4096;
                g2 = Y16 + (size_t)(b * LK + (f2 >> 6)) * DIM + e0 + ((f2 & 63) >> 1);
            }
            glds16(g2, (char*)&sS[buf][0] + ff);
        }
        if (heavy) {  // last 4KB chunk
            int ff = 32768 + t * 16;
            int f2 = ff - 4096;
            const f16* g2 = Y16 + (size_t)(b * LK + (f2 >> 6)) * DIM + e0 + ((f2 & 63) >> 1);
            glds16(g2, (char*)&sS[buf][0] + ff);
        }
    };
    auto compute = [&](int buf) {
        f16x8 th[4];
#pragma unroll
        for (int mi = 0; mi < 4; ++mi)
            th[mi] = *(const f16x8*)&sS[buf][(mi * 16 + ln15) * 32 + q * 8];
#pragma unroll
        for (int ni = 0; ni < 4; ++ni) {
            f16x8 y = *(const f16x8*)&sS[buf][2048 + (w * 64 + ni * 16 + ln15) * 32 + q * 8];
#pragma unroll
            for (int mi = 0; mi < 4; ++mi)
                acc[mi][ni] = MFMA16(th[mi], y, acc[mi][ni]);
        }
    };

    stage(0, 0);
    stage(1, 32);
    stage(2, 64);
    int cur = 0;
    for (int tt = 0; tt < 32; ++tt) {
        // wait until tile tt's loads landed (2 future tiles may stay in flight)
        if (tt < 30) {
            if (heavy) { WAITVM(10); } else { WAITVM(8); }
        } else if (tt == 30) {
            if (heavy) { WAITVM(5); } else { WAITVM(4); }
        } else {
            WAITVM(0);
        }
        BARRIER();
        CFENCE();
        __builtin_amdgcn_s_setprio(1);
        compute(cur);
        __builtin_amdgcn_s_setprio(0);
        CFENCE();
        BARRIER();
        if (tt < 29) stage(cur, (tt + 3) * 32);
        cur = (cur == 2) ? 0 : cur + 1;
    }

    // ---- softmax over 512 cols (8 waves x 64 cols) ----
    float zv[4];
#pragma unroll
    for (int ni = 0; ni < 4; ++ni) zv[ni] = Z[b * LK + w * 64 + ni * 16 + ln15];

    float rmx[4][4];
#pragma unroll
    for (int mi = 0; mi < 4; ++mi)
#pragma unroll
        for (int r = 0; r < 4; ++r) {
            float m = -3.0e38f;
#pragma unroll
            for (int ni = 0; ni < 4; ++ni) m = fmaxf(m, acc[mi][ni][r] + zv[ni]);
#pragma unroll
            for (int off = 1; off < 16; off <<= 1) m = fmaxf(m, __shfl_xor(m, off, 64));
            rmx[mi][r] = m;
        }
    if (ln15 == 0) {
#pragma unroll
        for (int mi = 0; mi < 4; ++mi)
#pragma unroll
            for (int r = 0; r < 4; ++r) redmax[mi * 16 + q * 4 + r][w] = rmx[mi][r];
    }
    __syncthreads();
#pragma unroll
    for (int mi = 0; mi < 4; ++mi)
#pragma unroll
        for (int r = 0; r < 4; ++r) {
            int row = mi * 16 + q * 4 + r;
            float m = redmax[row][0];
#pragma unroll
            for (int j = 1; j < 8; ++j) m = fmaxf(m, redmax[row][j]);
            rmx[mi][r] = m;
        }
    float rsm[4][4] = {};
#pragma unroll
    for (int mi = 0; mi < 4; ++mi)
#pragma unroll
        for (int ni = 0; ni < 4; ++ni)
#pragma unroll
            for (int r = 0; r < 4; ++r) {
                float e = __expf(acc[mi][ni][r] + zv[ni] - rmx[mi][r]);
                acc[mi][ni][r] = e;
                rsm[mi][r] += e;
            }
#pragma unroll
    for (int mi = 0; mi < 4; ++mi)
#pragma unroll
        for (int r = 0; r < 4; ++r) {
            float s = rsm[mi][r];
#pragma unroll
            for (int off = 1; off < 16; off <<= 1) s += __shfl_xor(s, off, 64);
            rsm[mi][r] = s;
        }
    if (ln15 == 0) {
#pragma unroll
        for (int mi = 0; mi < 4; ++mi)
#pragma unroll
            for (int r = 0; r < 4; ++r) redsum[mi * 16 + q * 4 + r][w] = rsm[mi][r];
    }
    __syncthreads();
    if (w == 0 && ln15 == 0) {
#pragma unroll
        for (int mi = 0; mi < 4; ++mi)
#pragma unroll
            for (int r = 0; r < 4; ++r) {
                int row = mi * 16 + q * 4 + r;
                float s = 0.f;
#pragma unroll
                for (int j = 0; j < 8; ++j) s += redsum[row][j];
                Lsum[b * LQ + l0 + row] = s;
            }
    }
#pragma unroll
    for (int mi = 0; mi < 4; ++mi)
#pragma unroll
        for (int ni = 0; ni < 4; ++ni)
#pragma unroll
            for (int r = 0; r < 4; ++r) {
                int row = l0 + mi * 16 + q * 4 + r;
                int col = w * 64 + ni * 16 + ln15;
                P[(size_t)(b * LQ + row) * LK + col] = (f16)acc[mi][ni][r];
            }
}

// ---------------------------------------------------------------------------
// K4: O = (P @ y) / Lsum via YT16. 128x128 tile, 256 thr, BK=32, linear
// glds staging, counted-vmcnt, grid 1024 (1D) with XCD batch-affinity
// (linear_id%8 == b%8: the 32 blocks sharing a batch's P+YT on one XCD).
// ---------------------------------------------------------------------------
__global__ __launch_bounds__(256) void k_pv(const f16* __restrict__ P,
                                            const f16* __restrict__ YT,
                                            const float* __restrict__ Lsum,
                                            float* __restrict__ O) {
    __shared__ __align__(16) f16 sA[2][128 * 32];
    __shared__ __align__(16) f16 sB[2][128 * 32];
    const int t = threadIdx.x;
    const int lane = t & 63, wid = t >> 6;
    const int ln15 = lane & 15, q = lane >> 4;
    const int wr = (wid >> 1) * 64, wc = (wid & 1) * 64;
    const int g = blockIdx.x;
    const int b = (g & 7) + 8 * (g >> 8);        // XCD-affine batch decode
    const int inner = (g >> 3) & 31;
    const int m0 = (inner >> 3) * 128, n0 = (inner & 7) * 128;
    floatx4 acc[4][4] = {};

    const int srow = t >> 2, scol = (t & 3) * 8;
    const f16* gA = P + (size_t)(b * LQ + m0 + srow) * LK + scol;
    const f16* gB = YT + (size_t)(b * DIM + n0 + srow) * LK + scol;

    auto stage = [&](int buf, int k0) {  // 4 glds16 per thread per tile
#pragma unroll
        for (int is = 0; is < 2; ++is) {
            glds16(gA + (size_t)(is * 64) * LK + k0,
                   (char*)&sA[buf][0] + is * 4096 + t * 16);
            glds16(gB + (size_t)(is * 64) * LK + k0,
                   (char*)&sB[buf][0] + is * 4096 + t * 16);
        }
    };
    auto compute = [&](int buf) {
        f16x8 a[4];
#pragma unroll
        for (int mi = 0; mi < 4; ++mi)
            a[mi] = *(const f16x8*)&sA[buf][(wr + mi * 16 + ln15) * 32 + q * 8];
#pragma unroll
        for (int ni = 0; ni < 4; ++ni) {
            f16x8 bv = *(const f16x8*)&sB[buf][(wc + ni * 16 + ln15) * 32 + q * 8];
#pragma unroll
            for (int mi = 0; mi < 4; ++mi) acc[mi][ni] = MFMA16(a[mi], bv, acc[mi][ni]);
        }
    };

    stage(0, 0);
    stage(1, 32);
    for (int tt = 0; tt < 16; ++tt) {
        if (tt < 15) { WAITVM(4); } else { WAITVM(0); }
        BARRIER();
        CFENCE();
        __builtin_amdgcn_s_setprio(1);
        compute(tt & 1);
        __builtin_amdgcn_s_setprio(0);
        CFENCE();
        BARRIER();
        if (tt < 14) stage(tt & 1, (tt + 2) * 32);
    }

    float invl[4][4];
#pragma unroll
    for (int mi = 0; mi < 4; ++mi)
#pragma unroll
        for (int r = 0; r < 4; ++r)
            invl[mi][r] = 1.0f / Lsum[b * LQ + m0 + wr + mi * 16 + q * 4 + r];
#pragma unroll
    for (int mi = 0; mi < 4; ++mi)
#pragma unroll
        for (int ni = 0; ni < 4; ++ni)
#pragma unroll
            for (int r = 0; r < 4; ++r)
                O[(size_t)(b * LQ + m0 + wr + mi * 16 + q * 4 + r) * DIM +
                  n0 + wc + ni * 16 + ln15] = acc[mi][ni][r] * invl[mi][r];
}

// ---------------------------------------------------------------------------
// Workspace layout (bytes), total ~86 MiB:
//   A:  0         X16 fp16 [16384][1024] (33,554,432); reused as YT16 after tgemm
//   B:  33554432  Y16 fp16 [32][512][1024] (33,554,432)
//   P:  67108864  P fp16 [32][512][512]    (16,777,216)
//       (head of P region doubles as WT16 fp16 [1024][1024] (2MB) before k_attn)
//   Gh: 83886080  (2,097,152)
//   c:  85983232 (4096)  z: 85987328 (65536)  L: 86052864 (65536)
//   partial: 86118400 (65536)
// d_out doubles as Th fp16 scratch (32 MB) between k_tgemm and k_attn;
// k_pv overwrites it with the final fp32 result.
// ---------------------------------------------------------------------------
extern "C" void kernel_launch(void* const* d_in, const int* in_sizes, int n_in,
                              void* d_out, int out_size, void* d_ws, size_t ws_size,
                              hipStream_t stream) {
    const float* ix = (const float*)d_in[0];
    const float* io = (const float*)d_in[1];
    const float* W = (const float*)d_in[2];
    const float* bb = (const float*)d_in[3];
    float* out = (float*)d_out;
    char* ws = (char*)d_ws;

    f16* X16 = (f16*)(ws);
    f16* YT16 = (f16*)(ws);  // same region, used after k_tgemm
    f16* Y16 = (f16*)(ws + 33554432);
    f16* P = (f16*)(ws + 67108864);
    f16* WT = (f16*)(ws + 67108864);  // overlays P region; dead before k_attn
    f16* Gh = (f16*)(ws + 83886080);
    float* c = (float*)(ws + 85983232);
    float* z = (float*)(ws + 85987328);
    float* L = (float*)(ws + 86052864);
    float* partial = (float*)(ws + 86118400);

    f16* Th = (f16*)d_out;

    k_cvec1<<<dim3(16, 16), dim3(256), 0, stream>>>(W, bb, partial);
    k_cvec2<<<dim3(4), dim3(256), 0, stream>>>(partial, c);
    k_wt16<<<dim3(16, 16), dim3(256), 0, stream>>>(W, WT);
    k_gram16<<<dim3(8, 8), dim3(256), 0, stream>>>(WT, Gh);
    k_prep_y<<<dim3(4096), dim3(256), 0, stream>>>(io, c, Y16, z);
    k_xsplit<<<dim3(8192), dim3(256), 0, stream>>>(ix, X16);
    k_tgemm<<<dim3(128, 8), dim3(256), 0, stream>>>(X16, Gh, Th);
    k_ytrans<<<dim3(32, 8, 16), dim3(256), 0, stream>>>(Y16, YT16);
    k_attn<<<dim3(256), dim3(512), 0, stream>>>(Th, Y16, z, P, L);
    k_pv<<<dim3(1024), dim3(256), 0, stream>>>(P, YT16, L, out);
}